// Round 5
// baseline (349.446 us; speedup 1.0000x reference)
//
#include <hip/hip_runtime.h>
#include <math.h>

#define BATCH   65536
#define NREL    500
#define HIDDEN  128
#define RDIM    64
#define EPS     1e-12f
#define SPLIT   2
#define PART1_BASE 504       // 504 % 8 == 0 -> part1 block lands on same XCD as part0
#define SLOT    512          // fixed bucket slot per relation (cnt ~ 131 +- 11)

// ws layout (bytes):
//   [0, 4MB)        sRec[NREL*SLOT] : int4 {item, srcNode, dstNode, pad}
//   [4MB, 4MB+2KB)  cursor[NREL]    : per-relation count (memset 0 each call)
#define WS_CUR_OFF  (NREL * SLOT * sizeof(int4))

typedef __attribute__((ext_vector_type(8))) short short8;   // 8 bf16 (4 VGPRs)
typedef __attribute__((ext_vector_type(4))) float f32x4;

__device__ __forceinline__ unsigned short f2bf(float x) {
    unsigned u = __float_as_uint(x);
    u += 0x7fffu + ((u >> 16) & 1u);   // RNE
    return (unsigned short)(u >> 16);
}

// ---- sort: direct slot reservation via device FAA (full occupancy, no LDS) ----
__global__ __launch_bounds__(256) void sort_k(
        const int* __restrict__ rel,
        const int* __restrict__ src,
        const int* __restrict__ dst,
        unsigned*  __restrict__ cursor,
        int4*      __restrict__ sRec) {
    const int item = blockIdx.x * 256 + threadIdx.x;
    const int r = rel[item];
    const int s = src[item];
    const int d = dst[item];
    unsigned p = atomicAdd(&cursor[r], 1u);          // ~131 FAA per line, 500 lines
    sRec[(unsigned)r * SLOT + p] = make_int4(item, s, d, 0);
}

// ---- main: per (relation, part) block; bf16 MFMA GEMM with pipelined gather ----
// A rows interleaved: row 2i = src(item i), row 2i+1 = dst(item i).
// Super-tile = 32 items = 64 rows; wave w owns rows w*16..w*16+15.
__global__ __launch_bounds__(256, 4) void proc_k(
        const float*    __restrict__ ent,
        const float*    __restrict__ relemb,
        const float*    __restrict__ proj,
        const unsigned* __restrict__ cursor,
        const int4*     __restrict__ sRec,
        float*          __restrict__ out) {
    // +8 half pad (272 B row stride) breaks the 256 B bank alias for frag reads
    __shared__ __align__(16) short Pt[RDIM][136];   // Pt[n=r][k=h] = P[h][r], bf16
    __shared__ __align__(16) short Ab[64][136];     // Ab[row][k=h], bf16
    __shared__ float Rlds[RDIM];

    const int tid  = threadIdx.x;
    const int w    = tid >> 6;
    const int lane = tid & 63;
    // XCD-paired mapping: part0 = blocks [0,500), part1 = blocks [504,1004)
    const int part = (blockIdx.x >= PART1_BASE) ? 1 : 0;
    const int rblk = blockIdx.x - part * PART1_BASE;
    if (rblk >= NREL) return;

    const unsigned start = (unsigned)rblk * SLOT;
    const unsigned cnt   = cursor[rblk];
    const unsigned end   = start + cnt;
    if (cnt == 0) return;   // uniform per block

    // staging role: row r_ = tid>>2 (0..63), quarter qq = tid&3 (32 h-elems)
    const int r_      = tid >> 2;
    const int qq      = tid & 3;
    const int sitm    = r_ >> 1;          // item within super-tile
    const int halfsel = r_ & 1;           // 0=src, 1=dst

    const int nst = (int)((cnt + 31u) >> 5);

    // ---- issue first tile's entity gather BEFORE P staging (overlap latencies) ----
    float4 pf[8];
    if (part < nst) {
        unsigned p = start + ((unsigned)part << 5) + (unsigned)sitm;
        if (p >= end) p = end - 1;
        int4 rec = sRec[p];
        int n = halfsel ? rec.z : rec.y;
        const float4* eg = (const float4*)(ent + (size_t)n * HIDDEN + qq * 32);
        #pragma unroll
        for (int j = 0; j < 8; j++) pf[j] = eg[j];
    }

    // ---- stage P -> bf16 transposed LDS (B^T layout: [n][k]) ----
    const float4* Pg4 = (const float4*)(proj + (size_t)rblk * (HIDDEN * RDIM));
    for (int f = tid; f < (HIDDEN * RDIM) / 4; f += 256) {
        float4 v = Pg4[f];
        int h  = f >> 4;          // 0..127
        int r0 = (f & 15) << 2;   // 0,4,..,60
        Pt[r0 + 0][h] = (short)f2bf(v.x);
        Pt[r0 + 1][h] = (short)f2bf(v.y);
        Pt[r0 + 2][h] = (short)f2bf(v.z);
        Pt[r0 + 3][h] = (short)f2bf(v.w);
    }
    if (tid < RDIM) Rlds[tid] = relemb[rblk * RDIM + tid];

    // compute role
    const int c    = lane & 15;           // C/D col (r-dim within N-tile)
    const int g    = lane >> 4;           // quad group
    const int q8   = g * 8;               // k offset within 32-chunk
    const int arow = (w << 4) + c;        // A row this lane reads

    for (int t = part; t < nst; t += SPLIT) {
        const unsigned base = start + ((unsigned)t << 5);

        // ---- write prefetched rows (fp32->bf16) into Ab ----
        {
            unsigned buf[16];
            #pragma unroll
            for (int j = 0; j < 8; j++) {
                buf[2 * j]     = ((unsigned)f2bf(pf[j].y) << 16) | f2bf(pf[j].x);
                buf[2 * j + 1] = ((unsigned)f2bf(pf[j].w) << 16) | f2bf(pf[j].z);
            }
            uint4* dstp = (uint4*)&Ab[r_][qq * 32];
            #pragma unroll
            for (int s = 0; s < 4; s++) dstp[s] = ((uint4*)buf)[s];
        }
        __syncthreads();   // Ab (and Pt on first iter) visible to all waves

        // ---- prefetch next tile's entity rows (hidden under MFMA + epilogue) ----
        if (t + SPLIT < nst) {
            unsigned p = start + ((unsigned)(t + SPLIT) << 5) + (unsigned)sitm;
            if (p >= end) p = end - 1;
            int4 rec = sRec[p];
            int n = halfsel ? rec.z : rec.y;
            const float4* eg = (const float4*)(ent + (size_t)n * HIDDEN + qq * 32);
            #pragma unroll
            for (int j = 0; j < 8; j++) pf[j] = eg[j];
        }

        // ---- MFMA: D[16 rows][64 r-dims] ----
        f32x4 acc[4];
        #pragma unroll
        for (int nt = 0; nt < 4; nt++) acc[nt] = (f32x4){0.f, 0.f, 0.f, 0.f};

        #pragma unroll
        for (int kk = 0; kk < 4; kk++) {
            short8 af = *(const short8*)&Ab[arow][kk * 32 + q8];
            #pragma unroll
            for (int nt = 0; nt < 4; nt++) {
                short8 bf = *(const short8*)&Pt[nt * 16 + c][kk * 32 + q8];
                acc[nt] = __builtin_amdgcn_mfma_f32_16x16x32_bf16(af, bf, acc[nt], 0, 0, 0);
            }
        }

        // ---- epilogue: rows 4g+j: j=0,1 -> item 2g s/d; j=2,3 -> item 2g+1 ----
        float ssq[4];
        #pragma unroll
        for (int j = 0; j < 4; j++) {
            ssq[j] = acc[0][j] * acc[0][j] + acc[1][j] * acc[1][j]
                   + acc[2][j] * acc[2][j] + acc[3][j] * acc[3][j];
        }
        #pragma unroll
        for (int m = 1; m < 16; m <<= 1) {
            #pragma unroll
            for (int j = 0; j < 4; j++) ssq[j] += __shfl_xor(ssq[j], m, 64);
        }
        float inv[4];
        #pragma unroll
        for (int j = 0; j < 4; j++) inv[j] = 1.0f / fmaxf(sqrtf(ssq[j]), EPS);

        float sa = 0.f, sb = 0.f;
        #pragma unroll
        for (int nt = 0; nt < 4; nt++) {
            float rv = Rlds[nt * 16 + c];
            float da = acc[nt][0] * inv[0] + rv - acc[nt][1] * inv[1];
            float db = acc[nt][2] * inv[2] + rv - acc[nt][3] * inv[3];
            sa = fmaf(da, da, sa);
            sb = fmaf(db, db, sb);
        }
        #pragma unroll
        for (int m = 1; m < 16; m <<= 1) {
            sa += __shfl_xor(sa, m, 64);
            sb += __shfl_xor(sb, m, 64);
        }
        if (c == 0) {
            unsigned pa = base + (unsigned)((w << 3) + (g << 1));
            if (pa < end)     out[sRec[pa].x]     = sqrtf(sa);
            if (pa + 1 < end) out[sRec[pa + 1].x] = sqrtf(sb);
        }
        __syncthreads();   // all waves done reading Ab before next overwrite
    }
}

extern "C" void kernel_launch(void* const* d_in, const int* in_sizes, int n_in,
                              void* d_out, int out_size, void* d_ws, size_t ws_size,
                              hipStream_t stream) {
    (void)in_sizes; (void)n_in; (void)out_size; (void)ws_size;
    const int*   src    = (const int*)d_in[0];
    const int*   rel    = (const int*)d_in[1];
    const int*   dst    = (const int*)d_in[2];
    const float* ent    = (const float*)d_in[3];
    const float* relemb = (const float*)d_in[4];
    const float* proj   = (const float*)d_in[5];
    float*       out    = (float*)d_out;

    int4*     sRec   = (int4*)d_ws;
    unsigned* cursor = (unsigned*)((char*)d_ws + WS_CUR_OFF);

    hipMemsetAsync(cursor, 0, NREL * sizeof(unsigned), stream);
    sort_k<<<BATCH / 256, 256, 0, stream>>>(rel, src, dst, cursor, sRec);
    proc_k<<<PART1_BASE + NREL, 256, 0, stream>>>(ent, relemb, proj, cursor, sRec, out);
}

// Round 6
// 328.409 us; speedup vs baseline: 1.0641x; 1.0641x over previous
//
#include <hip/hip_runtime.h>
#include <math.h>

#define BATCH   65536
#define NREL    500
#define HIDDEN  128
#define RDIM    64
#define EPS     1e-12f
#define SPLIT   2
#define SLOT    512          // fixed bucket slot per relation (cnt ~ 131 +- 11, 512 is ~33 sigma)
#define STHREADS 1024
#define SBLK    (BATCH / STHREADS)

// ws layout (bytes):
//   [0, 4MB)        sRec[NREL*SLOT] : int4 {item, srcNode, dstNode, pad}
//   [4MB, 4MB+2KB)  cursor[NREL]    : per-relation count (memset 0 each call)
#define WS_CUR_OFF  (NREL * SLOT * sizeof(int4))

typedef __attribute__((ext_vector_type(8))) short short8;   // 8 bf16 (4 VGPRs)
typedef __attribute__((ext_vector_type(4))) float f32x4;

__device__ __forceinline__ unsigned short f2bf(float x) {
    unsigned u = __float_as_uint(x);
    u += 0x7fffu + ((u >> 16) & 1u);   // RNE
    return (unsigned short)(u >> 16);
}

// ---- fused sort: LDS hist -> block-level global slot reservation -> int4 scatter ----
// Block-aggregated reservation keeps same-L2-line FAA contention ~16x lower than
// per-item FAA (R5 regression: 65536 direct FAAs over 32 lines cost ~+17 us).
__global__ __launch_bounds__(STHREADS) void sort_k(
        const int* __restrict__ rel,
        const int* __restrict__ src,
        const int* __restrict__ dst,
        unsigned*  __restrict__ cursor,
        int4*      __restrict__ sRec) {
    __shared__ unsigned lh[NREL];     // this block's per-relation count
    __shared__ unsigned lbase[NREL];  // reserved global base within relation
    __shared__ unsigned lcnt[NREL];   // local running cursor
    const int tid = threadIdx.x;
    for (int i = tid; i < NREL; i += STHREADS) { lh[i] = 0u; lcnt[i] = 0u; }
    __syncthreads();
    const int item = blockIdx.x * STHREADS + tid;
    const int r = rel[item];
    atomicAdd(&lh[r], 1u);
    __syncthreads();
    for (int i = tid; i < NREL; i += STHREADS) {
        unsigned c = lh[i];
        if (c) lbase[i] = atomicAdd(&cursor[i], c);   // device-scope FAA, 1 per (block,rel)
    }
    __syncthreads();
    unsigned p = (unsigned)r * SLOT + lbase[r] + atomicAdd(&lcnt[r], 1u);
    sRec[p] = make_int4(item, src[item], dst[item], 0);
}

// ---- main: per (relation, part) block; bf16 MFMA GEMM with pipelined gather ----
// A rows interleaved: row 2i = src(item i), row 2i+1 = dst(item i).
// Super-tile = 32 items = 64 rows; wave w owns rows w*16..w*16+15.
__global__ __launch_bounds__(256, 4) void proc_k(
        const float*    __restrict__ ent,
        const float*    __restrict__ relemb,
        const float*    __restrict__ proj,
        const unsigned* __restrict__ cursor,
        const int4*     __restrict__ sRec,
        float*          __restrict__ out) {
    // +8 half pad (272 B row stride) breaks the 256 B bank alias for frag reads
    __shared__ __align__(16) short Pt[RDIM][136];   // Pt[n=r][k=h] = P[h][r], bf16
    __shared__ __align__(16) short Ab[64][136];     // Ab[row][k=h], bf16
    __shared__ float Rlds[RDIM];

    const int tid  = threadIdx.x;
    const int w    = tid >> 6;
    const int lane = tid & 63;
    const int rblk = blockIdx.x / SPLIT;
    const int part = blockIdx.x % SPLIT;

    const unsigned start = (unsigned)rblk * SLOT;
    const unsigned cnt   = cursor[rblk];
    const unsigned end   = start + cnt;
    if (cnt == 0) return;   // uniform per block

    // staging role: row r_ = tid>>2 (0..63), quarter qq = tid&3 (32 h-elems)
    const int r_      = tid >> 2;
    const int qq      = tid & 3;
    const int sitm    = r_ >> 1;          // item within super-tile
    const int halfsel = r_ & 1;           // 0=src, 1=dst

    const int nst = (int)((cnt + 31u) >> 5);

    // ---- issue first tile's entity gather BEFORE P staging (overlap latencies) ----
    float4 pf[8];
    if (part < nst) {
        unsigned p = start + ((unsigned)part << 5) + (unsigned)sitm;
        if (p >= end) p = end - 1;
        int4 rec = sRec[p];
        int n = halfsel ? rec.z : rec.y;
        const float4* eg = (const float4*)(ent + (size_t)n * HIDDEN + qq * 32);
        #pragma unroll
        for (int j = 0; j < 8; j++) pf[j] = eg[j];
    }

    // ---- stage P -> bf16 transposed LDS (B^T layout: [n][k]) ----
    const float4* Pg4 = (const float4*)(proj + (size_t)rblk * (HIDDEN * RDIM));
    for (int f = tid; f < (HIDDEN * RDIM) / 4; f += 256) {
        float4 v = Pg4[f];
        int h  = f >> 4;          // 0..127
        int r0 = (f & 15) << 2;   // 0,4,..,60
        Pt[r0 + 0][h] = (short)f2bf(v.x);
        Pt[r0 + 1][h] = (short)f2bf(v.y);
        Pt[r0 + 2][h] = (short)f2bf(v.z);
        Pt[r0 + 3][h] = (short)f2bf(v.w);
    }
    if (tid < RDIM) Rlds[tid] = relemb[rblk * RDIM + tid];

    // compute role
    const int c    = lane & 15;           // C/D col (r-dim within N-tile)
    const int g    = lane >> 4;           // quad group
    const int q8   = g * 8;               // k offset within 32-chunk
    const int arow = (w << 4) + c;        // A row this lane reads

    for (int t = part; t < nst; t += SPLIT) {
        const unsigned base = start + ((unsigned)t << 5);

        // ---- write prefetched rows (fp32->bf16) into Ab ----
        {
            unsigned buf[16];
            #pragma unroll
            for (int j = 0; j < 8; j++) {
                buf[2 * j]     = ((unsigned)f2bf(pf[j].y) << 16) | f2bf(pf[j].x);
                buf[2 * j + 1] = ((unsigned)f2bf(pf[j].w) << 16) | f2bf(pf[j].z);
            }
            uint4* dstp = (uint4*)&Ab[r_][qq * 32];
            #pragma unroll
            for (int s = 0; s < 4; s++) dstp[s] = ((uint4*)buf)[s];
        }
        __syncthreads();   // Ab (and Pt on first iter) visible to all waves

        // ---- prefetch next tile's entity rows (hidden under MFMA + epilogue) ----
        if (t + SPLIT < nst) {
            unsigned p = start + ((unsigned)(t + SPLIT) << 5) + (unsigned)sitm;
            if (p >= end) p = end - 1;
            int4 rec = sRec[p];
            int n = halfsel ? rec.z : rec.y;
            const float4* eg = (const float4*)(ent + (size_t)n * HIDDEN + qq * 32);
            #pragma unroll
            for (int j = 0; j < 8; j++) pf[j] = eg[j];
        }

        // ---- MFMA: D[16 rows][64 r-dims] ----
        f32x4 acc[4];
        #pragma unroll
        for (int nt = 0; nt < 4; nt++) acc[nt] = (f32x4){0.f, 0.f, 0.f, 0.f};

        #pragma unroll
        for (int kk = 0; kk < 4; kk++) {
            short8 af = *(const short8*)&Ab[arow][kk * 32 + q8];
            #pragma unroll
            for (int nt = 0; nt < 4; nt++) {
                short8 bf = *(const short8*)&Pt[nt * 16 + c][kk * 32 + q8];
                acc[nt] = __builtin_amdgcn_mfma_f32_16x16x32_bf16(af, bf, acc[nt], 0, 0, 0);
            }
        }

        // ---- epilogue: rows 4g+j: j=0,1 -> item 2g s/d; j=2,3 -> item 2g+1 ----
        float ssq[4];
        #pragma unroll
        for (int j = 0; j < 4; j++) {
            ssq[j] = acc[0][j] * acc[0][j] + acc[1][j] * acc[1][j]
                   + acc[2][j] * acc[2][j] + acc[3][j] * acc[3][j];
        }
        #pragma unroll
        for (int m = 1; m < 16; m <<= 1) {
            #pragma unroll
            for (int j = 0; j < 4; j++) ssq[j] += __shfl_xor(ssq[j], m, 64);
        }
        float inv[4];
        #pragma unroll
        for (int j = 0; j < 4; j++) inv[j] = 1.0f / fmaxf(sqrtf(ssq[j]), EPS);

        float sa = 0.f, sb = 0.f;
        #pragma unroll
        for (int nt = 0; nt < 4; nt++) {
            float rv = Rlds[nt * 16 + c];
            float da = acc[nt][0] * inv[0] + rv - acc[nt][1] * inv[1];
            float db = acc[nt][2] * inv[2] + rv - acc[nt][3] * inv[3];
            sa = fmaf(da, da, sa);
            sb = fmaf(db, db, sb);
        }
        #pragma unroll
        for (int m = 1; m < 16; m <<= 1) {
            sa += __shfl_xor(sa, m, 64);
            sb += __shfl_xor(sb, m, 64);
        }
        if (c == 0) {
            unsigned pa = base + (unsigned)((w << 3) + (g << 1));
            if (pa < end)     out[sRec[pa].x]     = sqrtf(sa);
            if (pa + 1 < end) out[sRec[pa + 1].x] = sqrtf(sb);
        }
        __syncthreads();   // all waves done reading Ab before next overwrite
    }
}

extern "C" void kernel_launch(void* const* d_in, const int* in_sizes, int n_in,
                              void* d_out, int out_size, void* d_ws, size_t ws_size,
                              hipStream_t stream) {
    (void)in_sizes; (void)n_in; (void)out_size; (void)ws_size;
    const int*   src    = (const int*)d_in[0];
    const int*   rel    = (const int*)d_in[1];
    const int*   dst    = (const int*)d_in[2];
    const float* ent    = (const float*)d_in[3];
    const float* relemb = (const float*)d_in[4];
    const float* proj   = (const float*)d_in[5];
    float*       out    = (float*)d_out;

    int4*     sRec   = (int4*)d_ws;
    unsigned* cursor = (unsigned*)((char*)d_ws + WS_CUR_OFF);

    hipMemsetAsync(cursor, 0, NREL * sizeof(unsigned), stream);
    sort_k<<<SBLK, STHREADS, 0, stream>>>(rel, src, dst, cursor, sRec);
    proc_k<<<NREL * SPLIT, 256, 0, stream>>>(ent, relemb, proj, cursor, sRec, out);
}